// Round 1
// 10308.324 us; speedup vs baseline: 1.1272x; 1.1272x over previous
//
#include <hip/hip_runtime.h>

// GRU encoder-decoder, persistent 2-wave k-split fp32 design.
// B=8192, H=64, 512 enc + 180 dec steps. 1024 blocks x 128 threads:
// each block owns 8 batch elements; the block's two waves split the
// k-reduction of every GEMM (wave w sums k in [32w,32w+32)).
// Partial sums are exchanged via LDS; wave0 gates cell0, wave1 gates
// cell1 + output. 2 waves/SIMD hide L2-weight-stream + LDS latency
// (previous 1-wave/SIMD design was 40% stalled at VALUBusy=60%).
// Lane j owns gate rows {j, 64+j, 128+j}; weight reuse stays 8 FMA/value.

#define HSTR 12   // 8 batch + 4 pad floats: keeps float4 rows 16B-aligned

struct Params {
  const float *x;
  const float *wih0e, *bih0e, *bhh0e, *bih1e, *bhh1e;
  const float *wih0d, *bih0d, *bhh0d, *bih1d, *bhh1d;
  const float *outW, *outb;
  const float *wt;   // [6][64][64][3] transposed weights in d_ws
  float *out;
};

__device__ __forceinline__ float sgm(float v) { return 1.f / (1.f + __expf(-v)); }
__device__ __forceinline__ float th(float v)  { float e = __expf(2.f * v); return 1.f - 2.f / (e + 1.f); }

// Transpose the six 192x64 matrices into [k][j][g] packing (g = gate block 0..2,
// row = g*64+j, col = k). dst[i], i = k*192 + j*3 + g  <-  src[(g*64+j)*64 + k].
__global__ void prep_w(const float* s0, const float* s1, const float* s2,
                       const float* s3, const float* s4, const float* s5, float* dst) {
  const float* srcs[6] = {s0, s1, s2, s3, s4, s5};
  const float* s = srcs[blockIdx.x];
  float* o = dst + blockIdx.x * 12288;
  for (int i = threadIdx.x; i < 12288; i += blockDim.x) {
    int g = i % 3, jj = (i / 3) % 64, k = i / 192;
    o[i] = s[(g * 64 + jj) * 64 + k];
  }
}

// Half-K single GEMM: ah[b][g] += sum_{k=k0..k0+31} hs[k][b] * wt[k][j][g]
__device__ __forceinline__ void gemm1h(const float* wt, const float* hs, int j,
                                       int k0, float ah[8][3]) {
  const float* w = wt + k0 * 192;     // rows k0.., each 192 floats (64 j x 3)
  float3 wA[8];
#pragma unroll
  for (int u = 0; u < 8; ++u) wA[u] = *(const float3*)(w + (u * 64 + j) * 3);
  for (int kb = 0; kb < 32; kb += 8) {
    int kn = (kb + 8) & 31;             // wraps to 0 on last block (harmless reload)
    float3 wB[8];
#pragma unroll
    for (int u = 0; u < 8; ++u) wB[u] = *(const float3*)(w + ((kn + u) * 64 + j) * 3);
#pragma unroll
    for (int u = 0; u < 8; ++u) {
      int k = k0 + kb + u;
      float4 a0 = *(const float4*)&hs[k * HSTR];
      float4 a1 = *(const float4*)&hs[k * HSTR + 4];
      float hv[8] = {a0.x, a0.y, a0.z, a0.w, a1.x, a1.y, a1.z, a1.w};
#pragma unroll
      for (int b = 0; b < 8; ++b) {
        ah[b][0] += hv[b] * wA[u].x;
        ah[b][1] += hv[b] * wA[u].y;
        ah[b][2] += hv[b] * wA[u].z;
      }
    }
#pragma unroll
    for (int u = 0; u < 8; ++u) wA[u] = wB[u];
  }
}

// Half-K dual GEMM: ai += Wih^T-slice @ xs,  ah += Whh^T-slice @ hs  (k half)
__device__ __forceinline__ void gemm2h(const float* wi_, const float* wh_,
                                       const float* xs, const float* hs, int j,
                                       int k0, float ai[8][3], float ah[8][3]) {
  const float* wi = wi_ + k0 * 192;
  const float* wh = wh_ + k0 * 192;
  float3 wiA[4], whA[4];
#pragma unroll
  for (int u = 0; u < 4; ++u) {
    wiA[u] = *(const float3*)(wi + (u * 64 + j) * 3);
    whA[u] = *(const float3*)(wh + (u * 64 + j) * 3);
  }
  for (int kb = 0; kb < 32; kb += 4) {
    int kn = (kb + 4) & 31;
    float3 wiB[4], whB[4];
#pragma unroll
    for (int u = 0; u < 4; ++u) {
      wiB[u] = *(const float3*)(wi + ((kn + u) * 64 + j) * 3);
      whB[u] = *(const float3*)(wh + ((kn + u) * 64 + j) * 3);
    }
#pragma unroll
    for (int u = 0; u < 4; ++u) {
      int k = k0 + kb + u;
      float4 a0 = *(const float4*)&xs[k * HSTR];
      float4 a1 = *(const float4*)&xs[k * HSTR + 4];
      float4 c0 = *(const float4*)&hs[k * HSTR];
      float4 c1 = *(const float4*)&hs[k * HSTR + 4];
      float xv[8] = {a0.x, a0.y, a0.z, a0.w, a1.x, a1.y, a1.z, a1.w};
      float hv[8] = {c0.x, c0.y, c0.z, c0.w, c1.x, c1.y, c1.z, c1.w};
#pragma unroll
      for (int b = 0; b < 8; ++b) {
        ai[b][0] += xv[b] * wiA[u].x;
        ai[b][1] += xv[b] * wiA[u].y;
        ai[b][2] += xv[b] * wiA[u].z;
        ah[b][0] += hv[b] * whA[u].x;
        ah[b][1] += hv[b] * whA[u].y;
        ah[b][2] += hv[b] * whA[u].z;
      }
    }
#pragma unroll
    for (int u = 0; u < 4; ++u) { wiA[u] = wiB[u]; whA[u] = whB[u]; }
  }
}

__global__ __launch_bounds__(128, 2) void gru_main(Params p) {
  __shared__ __align__(16) float h0s[64 * HSTR];
  __shared__ __align__(16) float h1s[64 * HSTR];
  __shared__ float ex[32 * 64];   // partial-sum exchange, layout [i][j]
  __shared__ float prevs[8];
  const int j = threadIdx.x & 63;        // lane = gate index j
  const int wid = threadIdx.x >> 6;      // wave 0 / wave 1
  const int k0 = wid * 32;               // this wave's k half
  const int b0 = blockIdx.x * 8;         // batch base

  // ---- per-lane biases / tiny input weights (loaded by both waves; cheap) ----
  float bi0e[3], bh0e[3], bi1e[3], bh1e[3], wx0[3][2];
  float bi0d[3], bh0d[3], bi1d[3], bh1d[3], wd0[3];
#pragma unroll
  for (int g = 0; g < 3; ++g) {
    int r = g * 64 + j;
    bi0e[g] = p.bih0e[r]; bh0e[g] = p.bhh0e[r];
    bi1e[g] = p.bih1e[r]; bh1e[g] = p.bhh1e[r];
    wx0[g][0] = p.wih0e[2 * r]; wx0[g][1] = p.wih0e[2 * r + 1];
    bi0d[g] = p.bih0d[r]; bh0d[g] = p.bhh0d[r];
    bi1d[g] = p.bih1d[r]; bh1d[g] = p.bhh1d[r];
    wd0[g] = p.wih0d[r];
  }
  const float oW = p.outW[j], ob = p.outb[0];

  const float* wE0  = p.wt;
  const float* wE1i = p.wt + 12288;
  const float* wE1h = p.wt + 24576;
  const float* wD0  = p.wt + 36864;
  const float* wD1i = p.wt + 49152;
  const float* wD1h = p.wt + 61440;

  float h0own[8], h1own[8];
#pragma unroll
  for (int b = 0; b < 8; ++b) { h0own[b] = 0.f; h1own[b] = 0.f; }
  if (wid == 0) {
    *(float4*)&h0s[j * HSTR]     = make_float4(0, 0, 0, 0);
    *(float4*)&h0s[j * HSTR + 4] = make_float4(0, 0, 0, 0);
  } else {
    *(float4*)&h1s[j * HSTR]     = make_float4(0, 0, 0, 0);
    *(float4*)&h1s[j * HSTR + 4] = make_float4(0, 0, 0, 0);
    if (j < 8) prevs[j] = 0.f;
  }
  __syncthreads();

  // =================== encoder: 512 steps ===================
  for (int t = 0; t < 512; ++t) {
    // ---- cell0 partial (both waves, k halves) ----
    float ah[8][3];
#pragma unroll
    for (int b = 0; b < 8; ++b) { ah[b][0] = 0.f; ah[b][1] = 0.f; ah[b][2] = 0.f; }
    gemm1h(wE0, h0s, j, k0, ah);
    if (wid) {
#pragma unroll
      for (int b = 0; b < 8; ++b) {
        ex[(b * 3 + 0) * 64 + j] = ah[b][0];
        ex[(b * 3 + 1) * 64 + j] = ah[b][1];
        ex[(b * 3 + 2) * 64 + j] = ah[b][2];
      }
    }
    __syncthreads();   // A: ex(cell0) ready; h1s/prevs from prev step ready
    if (!wid) {
#pragma unroll
      for (int b = 0; b < 8; ++b) {
        float2 xx = *(const float2*)(p.x + ((size_t)(b0 + b) * 512 + t) * 2);
        float a0 = ah[b][0] + ex[(b * 3 + 0) * 64 + j];
        float a1 = ah[b][1] + ex[(b * 3 + 1) * 64 + j];
        float a2 = ah[b][2] + ex[(b * 3 + 2) * 64 + j];
        float ir  = bi0e[0] + wx0[0][0] * xx.x + wx0[0][1] * xx.y;
        float iz  = bi0e[1] + wx0[1][0] * xx.x + wx0[1][1] * xx.y;
        float inn = bi0e[2] + wx0[2][0] * xx.x + wx0[2][1] * xx.y;
        float r = sgm(ir + bh0e[0] + a0);
        float z = sgm(iz + bh0e[1] + a1);
        float n = th(inn + r * (bh0e[2] + a2));
        h0own[b] = (1.f - z) * n + z * h0own[b];
      }
      *(float4*)&h0s[j * HSTR]     = make_float4(h0own[0], h0own[1], h0own[2], h0own[3]);
      *(float4*)&h0s[j * HSTR + 4] = make_float4(h0own[4], h0own[5], h0own[6], h0own[7]);
    }
    __syncthreads();   // B: h0s(new) ready
    // ---- cell1 partial (both waves, k halves) ----
    float ai[8][3], ah1[8][3];
#pragma unroll
    for (int b = 0; b < 8; ++b) {
      ai[b][0] = 0.f; ai[b][1] = 0.f; ai[b][2] = 0.f;
      ah1[b][0] = 0.f; ah1[b][1] = 0.f; ah1[b][2] = 0.f;
    }
    gemm2h(wE1i, wE1h, h0s, h1s, j, k0, ai, ah1);
    if (!wid) {
#pragma unroll
      for (int b = 0; b < 8; ++b) {
        ex[(b * 4 + 0) * 64 + j] = ai[b][0] + ah1[b][0];
        ex[(b * 4 + 1) * 64 + j] = ai[b][1] + ah1[b][1];
        ex[(b * 4 + 2) * 64 + j] = ai[b][2];
        ex[(b * 4 + 3) * 64 + j] = ah1[b][2];
      }
    }
    __syncthreads();   // C: ex(cell1) ready
    if (wid) {
#pragma unroll
      for (int b = 0; b < 8; ++b) {
        float s0 = ai[b][0] + ah1[b][0] + ex[(b * 4 + 0) * 64 + j];
        float s1 = ai[b][1] + ah1[b][1] + ex[(b * 4 + 1) * 64 + j];
        float s2 = ai[b][2]             + ex[(b * 4 + 2) * 64 + j];
        float s3 = ah1[b][2]            + ex[(b * 4 + 3) * 64 + j];
        float r = sgm(s0 + bi1e[0] + bh1e[0]);
        float z = sgm(s1 + bi1e[1] + bh1e[1]);
        float n = th(s2 + bi1e[2] + r * (bh1e[2] + s3));
        h1own[b] = (1.f - z) * n + z * h1own[b];
      }
      *(float4*)&h1s[j * HSTR]     = make_float4(h1own[0], h1own[1], h1own[2], h1own[3]);
      *(float4*)&h1s[j * HSTR + 4] = make_float4(h1own[4], h1own[5], h1own[6], h1own[7]);
    }
  }

  // =================== decoder: 180 steps ===================
  for (int t = 0; t < 180; ++t) {
    // ---- cell0 partial ----
    float ah[8][3];
#pragma unroll
    for (int b = 0; b < 8; ++b) { ah[b][0] = 0.f; ah[b][1] = 0.f; ah[b][2] = 0.f; }
    gemm1h(wD0, h0s, j, k0, ah);
    if (wid) {
#pragma unroll
      for (int b = 0; b < 8; ++b) {
        ex[(b * 3 + 0) * 64 + j] = ah[b][0];
        ex[(b * 3 + 1) * 64 + j] = ah[b][1];
        ex[(b * 3 + 2) * 64 + j] = ah[b][2];
      }
    }
    __syncthreads();   // A: ex(cell0) + h1s/prevs from prev step ready
    if (!wid) {
#pragma unroll
      for (int b = 0; b < 8; ++b) {
        float pv = prevs[b];
        float a0 = ah[b][0] + ex[(b * 3 + 0) * 64 + j];
        float a1 = ah[b][1] + ex[(b * 3 + 1) * 64 + j];
        float a2 = ah[b][2] + ex[(b * 3 + 2) * 64 + j];
        float r = sgm(bi0d[0] + wd0[0] * pv + bh0d[0] + a0);
        float z = sgm(bi0d[1] + wd0[1] * pv + bh0d[1] + a1);
        float n = th(bi0d[2] + wd0[2] * pv + r * (bh0d[2] + a2));
        h0own[b] = (1.f - z) * n + z * h0own[b];
      }
      *(float4*)&h0s[j * HSTR]     = make_float4(h0own[0], h0own[1], h0own[2], h0own[3]);
      *(float4*)&h0s[j * HSTR + 4] = make_float4(h0own[4], h0own[5], h0own[6], h0own[7]);
    }
    __syncthreads();   // B: h0s(new) ready
    // ---- cell1 partial ----
    float ai[8][3], ah1[8][3];
#pragma unroll
    for (int b = 0; b < 8; ++b) {
      ai[b][0] = 0.f; ai[b][1] = 0.f; ai[b][2] = 0.f;
      ah1[b][0] = 0.f; ah1[b][1] = 0.f; ah1[b][2] = 0.f;
    }
    gemm2h(wD1i, wD1h, h0s, h1s, j, k0, ai, ah1);
    if (!wid) {
#pragma unroll
      for (int b = 0; b < 8; ++b) {
        ex[(b * 4 + 0) * 64 + j] = ai[b][0] + ah1[b][0];
        ex[(b * 4 + 1) * 64 + j] = ai[b][1] + ah1[b][1];
        ex[(b * 4 + 2) * 64 + j] = ai[b][2];
        ex[(b * 4 + 3) * 64 + j] = ah1[b][2];
      }
    }
    __syncthreads();   // C: ex(cell1) ready
    if (wid) {
#pragma unroll
      for (int b = 0; b < 8; ++b) {
        float s0 = ai[b][0] + ah1[b][0] + ex[(b * 4 + 0) * 64 + j];
        float s1 = ai[b][1] + ah1[b][1] + ex[(b * 4 + 1) * 64 + j];
        float s2 = ai[b][2]             + ex[(b * 4 + 2) * 64 + j];
        float s3 = ah1[b][2]            + ex[(b * 4 + 3) * 64 + j];
        float r = sgm(s0 + bi1d[0] + bh1d[0]);
        float z = sgm(s1 + bi1d[1] + bh1d[1]);
        float n = th(s2 + bi1d[2] + r * (bh1d[2] + s3));
        h1own[b] = (1.f - z) * n + z * h1own[b];
      }
      *(float4*)&h1s[j * HSTR]     = make_float4(h1own[0], h1own[1], h1own[2], h1own[3]);
      *(float4*)&h1s[j * HSTR + 4] = make_float4(h1own[4], h1own[5], h1own[6], h1own[7]);

      // ---- output: cv[b] = sum_j outW[j]*h1[b][j] + ob; butterfly over 64 lanes
      float v[8];
#pragma unroll
      for (int b = 0; b < 8; ++b) v[b] = oW * h1own[b];
#pragma unroll
      for (int off = 32; off >= 1; off >>= 1) {
#pragma unroll
        for (int b = 0; b < 8; ++b) v[b] += __shfl_xor(v[b], off, 64);
      }
      float ov = v[0] + ob;
#pragma unroll
      for (int b = 1; b < 8; ++b) ov = (j == b) ? (v[b] + ob) : ov;
      if (j < 8) {
        p.out[(size_t)(b0 + j) * 180 + t] = ov;
        prevs[j] = ov;                     // autoregressive feedback
      }
    }
  }
}

extern "C" void kernel_launch(void* const* d_in, const int* in_sizes, int n_in,
                              void* d_out, int out_size, void* d_ws, size_t ws_size,
                              hipStream_t stream) {
  // input order: 0 x, 1 enc_Wih0, 2 enc_Whh0, 3 enc_bih0, 4 enc_bhh0,
  // 5 enc_Wih1, 6 enc_Whh1, 7 enc_bih1, 8 enc_bhh1, 9 dec_Wih0, 10 dec_Whh0,
  // 11 dec_bih0, 12 dec_bhh0, 13 dec_Wih1, 14 dec_Whh1, 15 dec_bih1,
  // 16 dec_bhh1, 17 out_W, 18 out_b
  float* wt = (float*)d_ws;  // needs 6*12288*4 = 294912 B of scratch

  prep_w<<<dim3(6), dim3(256), 0, stream>>>(
      (const float*)d_in[2], (const float*)d_in[5], (const float*)d_in[6],
      (const float*)d_in[10], (const float*)d_in[13], (const float*)d_in[14], wt);

  Params p;
  p.x = (const float*)d_in[0];
  p.wih0e = (const float*)d_in[1];
  p.bih0e = (const float*)d_in[3];
  p.bhh0e = (const float*)d_in[4];
  p.bih1e = (const float*)d_in[7];
  p.bhh1e = (const float*)d_in[8];
  p.wih0d = (const float*)d_in[9];
  p.bih0d = (const float*)d_in[11];
  p.bhh0d = (const float*)d_in[12];
  p.bih1d = (const float*)d_in[15];
  p.bhh1d = (const float*)d_in[16];
  p.outW = (const float*)d_in[17];
  p.outb = (const float*)d_in[18];
  p.wt = wt;
  p.out = (float*)d_out;

  gru_main<<<dim3(1024), dim3(128), 0, stream>>>(p);
}

// Round 2
// 9607.760 us; speedup vs baseline: 1.2094x; 1.0729x over previous
//
#include <hip/hip_runtime.h>

// GRU encoder-decoder, persistent 4-wave symmetric k-split fp32 design.
// B=8192, H=64, 512 enc + 180 dec steps. 1024 blocks x 256 threads:
// each block owns 8 batch elements; the 4 waves split the k-reduction
// (wave w sums k in [16w,16w+16)) of every GEMM, and gating/output is
// batch-split (wave w gates batches {2w,2w+1} for BOTH cells) so all
// phases are symmetric -> barrier stalls are minimal and uncorrelated
// work fills the SIMD. 16 waves/CU = 4/SIMD (VGPR budget <=128).
// Lane j owns gate rows {j, 64+j, 128+j}; weight reuse stays 8 FMA/value
// (block loads full-k weight set once per step: 147 MB/step chip-wide,
// well under the 34.5 TB/s L2 ceiling even at the 2.66 ms FMA floor).
// Partial-sum exchange is packed float4 rows -> b128 LDS ops.

#define HSTR 12   // 8 batch + 4 pad floats: keeps float4 rows 16B-aligned

struct Params {
  const float *x;
  const float *wih0e, *bih0e, *bhh0e, *bih1e, *bhh1e;
  const float *wih0d, *bih0d, *bhh0d, *bih1d, *bhh1d;
  const float *outW, *outb;
  const float *wt;   // [6][64][64][3] transposed weights in d_ws
  float *out;
};

__device__ __forceinline__ float sgm(float v) { return 1.f / (1.f + __expf(-v)); }
__device__ __forceinline__ float th(float v)  { float e = __expf(2.f * v); return 1.f - 2.f / (e + 1.f); }

// Transpose the six 192x64 matrices into [k][j][g] packing (g = gate block 0..2,
// row = g*64+j, col = k). dst[i], i = k*192 + j*3 + g  <-  src[(g*64+j)*64 + k].
__global__ void prep_w(const float* s0, const float* s1, const float* s2,
                       const float* s3, const float* s4, const float* s5, float* dst) {
  const float* srcs[6] = {s0, s1, s2, s3, s4, s5};
  const float* s = srcs[blockIdx.x];
  float* o = dst + blockIdx.x * 12288;
  for (int i = threadIdx.x; i < 12288; i += blockDim.x) {
    int g = i % 3, jj = (i / 3) % 64, k = i / 192;
    o[i] = s[(g * 64 + jj) * 64 + k];
  }
}

// cell0 partial: ah[b][g] += sum_{k=k0..k0+15} hs[k][b] * w[k][j][g]
__device__ __forceinline__ void pgemm1(const float* w, const float* hs, int j, int k0,
                                       float ah[8][3]) {
  const float* wp = w + (k0 * 64 + j) * 3;
#pragma unroll 4
  for (int kk = 0; kk < 16; ++kk) {
    float3 wv = *(const float3*)(wp + kk * 192);
    float4 a0 = *(const float4*)&hs[(k0 + kk) * HSTR];
    float4 a1 = *(const float4*)&hs[(k0 + kk) * HSTR + 4];
    float hv[8] = {a0.x, a0.y, a0.z, a0.w, a1.x, a1.y, a1.z, a1.w};
#pragma unroll
    for (int b = 0; b < 8; ++b) {
      ah[b][0] += hv[b] * wv.x;
      ah[b][1] += hv[b] * wv.y;
      ah[b][2] += hv[b] * wv.z;
    }
  }
}

// cell1 partial with 4 accumulators per batch:
//  ar = Wih1_r@x + Whh1_r@h ; az likewise ; ain = Wih1_n@x ; ahn = Whh1_n@h
__device__ __forceinline__ void pgemm2(const float* wi, const float* wh,
                                       const float* xs, const float* hs, int j, int k0,
                                       float ar[8], float az[8], float ain[8], float ahn[8]) {
  const float* wip = wi + (k0 * 64 + j) * 3;
  const float* whp = wh + (k0 * 64 + j) * 3;
#pragma unroll 2
  for (int kk = 0; kk < 16; ++kk) {
    float3 wiv = *(const float3*)(wip + kk * 192);
    float3 whv = *(const float3*)(whp + kk * 192);
    float4 x0 = *(const float4*)&xs[(k0 + kk) * HSTR];
    float4 x1 = *(const float4*)&xs[(k0 + kk) * HSTR + 4];
    float4 c0 = *(const float4*)&hs[(k0 + kk) * HSTR];
    float4 c1 = *(const float4*)&hs[(k0 + kk) * HSTR + 4];
    float xv[8] = {x0.x, x0.y, x0.z, x0.w, x1.x, x1.y, x1.z, x1.w};
    float hv[8] = {c0.x, c0.y, c0.z, c0.w, c1.x, c1.y, c1.z, c1.w};
#pragma unroll
    for (int b = 0; b < 8; ++b) {
      ar[b]  += xv[b] * wiv.x;  ar[b]  += hv[b] * whv.x;
      az[b]  += xv[b] * wiv.y;  az[b]  += hv[b] * whv.y;
      ain[b] += xv[b] * wiv.z;  ahn[b] += hv[b] * whv.z;
    }
  }
}

__global__ __launch_bounds__(256, 4) void gru_main(Params p) {
  __shared__ __align__(16) float h0s[64 * HSTR];
  __shared__ __align__(16) float h1s[64 * HSTR];
  __shared__ __align__(16) float ex[4 * 8 * 64 * 4];  // [writer_w][b][j][acc] float4 rows
  __shared__ float prevs[8];
  float4* exv = (float4*)ex;                          // index ((w*8+b)<<6)+j

  const int j   = threadIdx.x & 63;   // lane = gate index j (rows j,64+j,128+j)
  const int wid = threadIdx.x >> 6;   // wave 0..3
  const int k0  = wid * 16;           // this wave's k slice
  const int bg  = wid * 2;            // this wave gates batches bg, bg+1
  const int b0  = blockIdx.x * 8;     // batch base

  const float* wE0  = p.wt;
  const float* wE1i = p.wt + 12288;
  const float* wE1h = p.wt + 24576;
  const float* wD0  = p.wt + 36864;
  const float* wD1i = p.wt + 49152;
  const float* wD1h = p.wt + 61440;

  for (int i = threadIdx.x; i < 64 * HSTR; i += 256) { h0s[i] = 0.f; h1s[i] = 0.f; }
  if (threadIdx.x < 8) prevs[threadIdx.x] = 0.f;
  float h0own[2] = {0.f, 0.f}, h1own[2] = {0.f, 0.f};
  __syncthreads();

  // =================== encoder: 512 steps ===================
  {
    float bi0[3], bh0[3], bi1[3], bh1[3], wx[3][2];
#pragma unroll
    for (int g = 0; g < 3; ++g) {
      int r = g * 64 + j;
      bi0[g] = p.bih0e[r]; bh0[g] = p.bhh0e[r];
      bi1[g] = p.bih1e[r]; bh1[g] = p.bhh1e[r];
      wx[g][0] = p.wih0e[2 * r]; wx[g][1] = p.wih0e[2 * r + 1];
    }
    for (int t = 0; t < 512; ++t) {
      // ---- A: cell0 partial (all waves, k slices) ----
      float ah[8][3];
#pragma unroll
      for (int b = 0; b < 8; ++b) { ah[b][0] = 0.f; ah[b][1] = 0.f; ah[b][2] = 0.f; }
      pgemm1(wE0, h0s, j, k0, ah);
#pragma unroll
      for (int b = 0; b < 8; ++b)
        exv[((wid * 8 + b) << 6) + j] = make_float4(ah[b][0], ah[b][1], ah[b][2], 0.f);
      __syncthreads();  // 1: ex(cell0) ready
      // ---- B: gate0 for own 2 batches; publish h0 ----
#pragma unroll
      for (int i = 0; i < 2; ++i) {
        int b = bg + i;
        float s0 = 0.f, s1 = 0.f, s2 = 0.f;
#pragma unroll
        for (int w = 0; w < 4; ++w) {
          float4 q = exv[((w * 8 + b) << 6) + j];
          s0 += q.x; s1 += q.y; s2 += q.z;
        }
        float2 xx = *(const float2*)(p.x + ((size_t)(b0 + b) * 512 + t) * 2);
        float ir  = bi0[0] + wx[0][0] * xx.x + wx[0][1] * xx.y;
        float iz  = bi0[1] + wx[1][0] * xx.x + wx[1][1] * xx.y;
        float inn = bi0[2] + wx[2][0] * xx.x + wx[2][1] * xx.y;
        float r = sgm(ir + bh0[0] + s0);
        float z = sgm(iz + bh0[1] + s1);
        float n = th(inn + r * (bh0[2] + s2));
        h0own[i] = (1.f - z) * n + z * h0own[i];
      }
      *(float2*)&h0s[j * HSTR + bg] = make_float2(h0own[0], h0own[1]);
      __syncthreads();  // 2: h0s(new) complete
      // ---- C: cell1 partial ----
      float ar[8], az[8], ain[8], ahn[8];
#pragma unroll
      for (int b = 0; b < 8; ++b) { ar[b] = 0.f; az[b] = 0.f; ain[b] = 0.f; ahn[b] = 0.f; }
      pgemm2(wE1i, wE1h, h0s, h1s, j, k0, ar, az, ain, ahn);
#pragma unroll
      for (int b = 0; b < 8; ++b)
        exv[((wid * 8 + b) << 6) + j] = make_float4(ar[b], az[b], ain[b], ahn[b]);
      __syncthreads();  // 3: ex(cell1) ready
      // ---- D: gate1 for own 2 batches; publish h1 ----
#pragma unroll
      for (int i = 0; i < 2; ++i) {
        int b = bg + i;
        float sr = 0.f, sz = 0.f, si = 0.f, sh = 0.f;
#pragma unroll
        for (int w = 0; w < 4; ++w) {
          float4 q = exv[((w * 8 + b) << 6) + j];
          sr += q.x; sz += q.y; si += q.z; sh += q.w;
        }
        float r = sgm(sr + bi1[0] + bh1[0]);
        float z = sgm(sz + bi1[1] + bh1[1]);
        float n = th(si + bi1[2] + r * (bh1[2] + sh));
        h1own[i] = (1.f - z) * n + z * h1own[i];
      }
      *(float2*)&h1s[j * HSTR + bg] = make_float2(h1own[0], h1own[1]);
      __syncthreads();  // 4: protects ex reuse by next step's phase A
    }
  }

  // =================== decoder: 180 steps ===================
  {
    float bi0[3], bh0[3], bi1[3], bh1[3], wd[3];
#pragma unroll
    for (int g = 0; g < 3; ++g) {
      int r = g * 64 + j;
      bi0[g] = p.bih0d[r]; bh0[g] = p.bhh0d[r];
      bi1[g] = p.bih1d[r]; bh1[g] = p.bhh1d[r];
      wd[g] = p.wih0d[r];
    }
    const float oW = p.outW[j], ob = p.outb[0];

    for (int t = 0; t < 180; ++t) {
      // ---- A: cell0 partial ----
      float ah[8][3];
#pragma unroll
      for (int b = 0; b < 8; ++b) { ah[b][0] = 0.f; ah[b][1] = 0.f; ah[b][2] = 0.f; }
      pgemm1(wD0, h0s, j, k0, ah);
#pragma unroll
      for (int b = 0; b < 8; ++b)
        exv[((wid * 8 + b) << 6) + j] = make_float4(ah[b][0], ah[b][1], ah[b][2], 0.f);
      __syncthreads();  // 1
      // ---- B: gate0 (input = prev scalar) ----
#pragma unroll
      for (int i = 0; i < 2; ++i) {
        int b = bg + i;
        float s0 = 0.f, s1 = 0.f, s2 = 0.f;
#pragma unroll
        for (int w = 0; w < 4; ++w) {
          float4 q = exv[((w * 8 + b) << 6) + j];
          s0 += q.x; s1 += q.y; s2 += q.z;
        }
        float pv = prevs[b];
        float r = sgm(bi0[0] + wd[0] * pv + bh0[0] + s0);
        float z = sgm(bi0[1] + wd[1] * pv + bh0[1] + s1);
        float n = th(bi0[2] + wd[2] * pv + r * (bh0[2] + s2));
        h0own[i] = (1.f - z) * n + z * h0own[i];
      }
      *(float2*)&h0s[j * HSTR + bg] = make_float2(h0own[0], h0own[1]);
      __syncthreads();  // 2
      // ---- C: cell1 partial ----
      float ar[8], az[8], ain[8], ahn[8];
#pragma unroll
      for (int b = 0; b < 8; ++b) { ar[b] = 0.f; az[b] = 0.f; ain[b] = 0.f; ahn[b] = 0.f; }
      pgemm2(wD1i, wD1h, h0s, h1s, j, k0, ar, az, ain, ahn);
#pragma unroll
      for (int b = 0; b < 8; ++b)
        exv[((wid * 8 + b) << 6) + j] = make_float4(ar[b], az[b], ain[b], ahn[b]);
      __syncthreads();  // 3
      // ---- D: gate1 + output for own 2 batches ----
      float v[2];
#pragma unroll
      for (int i = 0; i < 2; ++i) {
        int b = bg + i;
        float sr = 0.f, sz = 0.f, si = 0.f, sh = 0.f;
#pragma unroll
        for (int w = 0; w < 4; ++w) {
          float4 q = exv[((w * 8 + b) << 6) + j];
          sr += q.x; sz += q.y; si += q.z; sh += q.w;
        }
        float r = sgm(sr + bi1[0] + bh1[0]);
        float z = sgm(sz + bi1[1] + bh1[1]);
        float n = th(si + bi1[2] + r * (bh1[2] + sh));
        h1own[i] = (1.f - z) * n + z * h1own[i];
        v[i] = oW * h1own[i];
      }
      *(float2*)&h1s[j * HSTR + bg] = make_float2(h1own[0], h1own[1]);
      // butterfly dot over 64 lanes for the 2 own batches
#pragma unroll
      for (int off = 32; off >= 1; off >>= 1) {
#pragma unroll
        for (int i = 0; i < 2; ++i) v[i] += __shfl_xor(v[i], off, 64);
      }
      if (j == 0) {
#pragma unroll
        for (int i = 0; i < 2; ++i) {
          float o = v[i] + ob;
          p.out[(size_t)(b0 + bg + i) * 180 + t] = o;
          prevs[bg + i] = o;                 // autoregressive feedback
        }
      }
      __syncthreads();  // 4: ex + prevs stable for next step
    }
  }
}

extern "C" void kernel_launch(void* const* d_in, const int* in_sizes, int n_in,
                              void* d_out, int out_size, void* d_ws, size_t ws_size,
                              hipStream_t stream) {
  // input order: 0 x, 1 enc_Wih0, 2 enc_Whh0, 3 enc_bih0, 4 enc_bhh0,
  // 5 enc_Wih1, 6 enc_Whh1, 7 enc_bih1, 8 enc_bhh1, 9 dec_Wih0, 10 dec_Whh0,
  // 11 dec_bih0, 12 dec_bhh0, 13 dec_Wih1, 14 dec_Whh1, 15 dec_bih1,
  // 16 dec_bhh1, 17 out_W, 18 out_b
  float* wt = (float*)d_ws;  // needs 6*12288*4 = 294912 B of scratch

  prep_w<<<dim3(6), dim3(256), 0, stream>>>(
      (const float*)d_in[2], (const float*)d_in[5], (const float*)d_in[6],
      (const float*)d_in[10], (const float*)d_in[13], (const float*)d_in[14], wt);

  Params p;
  p.x = (const float*)d_in[0];
  p.wih0e = (const float*)d_in[1];
  p.bih0e = (const float*)d_in[3];
  p.bhh0e = (const float*)d_in[4];
  p.bih1e = (const float*)d_in[7];
  p.bhh1e = (const float*)d_in[8];
  p.wih0d = (const float*)d_in[9];
  p.bih0d = (const float*)d_in[11];
  p.bhh0d = (const float*)d_in[12];
  p.bih1d = (const float*)d_in[15];
  p.bhh1d = (const float*)d_in[16];
  p.outW = (const float*)d_in[17];
  p.outb = (const float*)d_in[18];
  p.wt = wt;
  p.out = (float*)d_out;

  gru_main<<<dim3(1024), dim3(256), 0, stream>>>(p);
}

// Round 3
// 2464.685 us; speedup vs baseline: 4.7144x; 3.8982x over previous
//
#include <hip/hip_runtime.h>

// GRU encoder-decoder, MFMA split-precision (bf16x4-product) design.
// B=8192, H=64, 512 enc + 180 dec steps. 512 blocks x 256 threads (4 waves),
// 16 batches/block. Per step, the three GEMMs (16x192x64) run on the matrix
// pipe: mfma_f32_16x16x32_bf16 with W and h each split into bf16 hi+lo
// (RNE), 4 products accumulated in fp32 -> ~fp32 accuracy. The recurrence
// state h stays fp32 in gate-thread registers; only GEMM operands round.
// Waves split N=192 into 4x48 (3 N-tiles each); all weight B-fragments are
// held in VGPRs for the whole phase (144 VGPR/wave, zero steady weight
// traffic). h is exchanged via LDS in MFMA A-fragment layout; GEMM outputs
// via padded f32 exchange arrays (strides chosen bank-conflict-free).
// Round-2 evidence: VALU-issue-bound, 67% of issue was non-FMA overhead;
// this moves the 2.66ms-floor FMA work to MFMA (~0.2ms) and deletes the
// per-element extraction overhead.

typedef __attribute__((ext_vector_type(8))) short bf16x8;
typedef __attribute__((ext_vector_type(4))) float f32x4;

#define EXS 17            // ex row stride (floats): odd -> gate reads 2-way max
#define AHS 24            // aH per-batch stride (ushorts): 16 data + 8 pad
#define AHK (16*AHS + 8)  // aH per-kgroup stride (+8 pad spreads write banks)

struct Params {
  const float *x;
  const float *wih0e, *bih0e, *bhh0e, *bih1e, *bhh1e;
  const float *wih0d, *bih0d, *bhh0d, *bih1d, *bhh1d;
  const float *outW, *outb;
  const unsigned short *wt;   // [6][12 nt][2 kf][2 sp][64 lane][8 e] bf16 frags
  float *out;
};

__device__ __forceinline__ float sgm(float v) { return 1.f / (1.f + __expf(-v)); }
__device__ __forceinline__ float th(float v)  { float e = __expf(2.f * v); return 1.f - 2.f / (e + 1.f); }

// fp32 -> bf16 round-to-nearest-even (bit trick)
__device__ __forceinline__ unsigned short rbf(float v) {
  unsigned int u = __float_as_uint(v);
  return (unsigned short)((u + 0x7fffu + ((u >> 16) & 1u)) >> 16);
}
__device__ __forceinline__ float ubf(unsigned short h) {
  return __uint_as_float((unsigned int)h << 16);
}

__device__ __forceinline__ f32x4 mfma16(bf16x8 a, bf16x8 b, f32x4 c) {
  return __builtin_amdgcn_mfma_f32_16x16x32_bf16(a, b, c, 0, 0, 0);
}

// Preprocess the six 192x64 fp32 matrices into B-fragment bf16 hi/lo planes.
// B[k][n] = W[n][k]; frag (nt,kf,sp): lane l elem e holds
// B[k = kf*32 + (l>>4)*8 + e][n = nt*16 + (l&15)].
// Flat: dst[m][ ((nt*2+kf)*2+sp)*512 + l*8 + e ]
__global__ void prep_w(const float* s0, const float* s1, const float* s2,
                       const float* s3, const float* s4, const float* s5,
                       unsigned short* dst) {
  const float* srcs[6] = {s0, s1, s2, s3, s4, s5};
  const float* s = srcs[blockIdx.x];
  unsigned short* o = dst + blockIdx.x * 24576;
  for (int i = threadIdx.x; i < 24576; i += blockDim.x) {
    int e  = i & 7;
    int l  = (i >> 3) & 63;
    int sp = (i >> 9) & 1;
    int kf = (i >> 10) & 1;
    int nt = i >> 11;
    int n = nt * 16 + (l & 15);
    int k = kf * 32 + (l >> 4) * 8 + e;
    float v = s[n * 64 + k];
    unsigned short hi = rbf(v);
    unsigned short val = hi;
    if (sp) val = rbf(v - ubf(hi));
    o[i] = val;
  }
}

__global__ __launch_bounds__(256, 2) void gru_main(Params p) {
  __shared__ float exI[192 * EXS];
  __shared__ float exH[192 * EXS];
  __shared__ __align__(16) unsigned short aH0[8 * AHK];
  __shared__ __align__(16) unsigned short aH1[8 * AHK];
  __shared__ float prevs[16];

  const int tid  = threadIdx.x;
  const int lane = tid & 63;
  const int w    = tid >> 6;       // wave 0..3
  const int j    = lane;           // gate row index (rows j, 64+j, 128+j)
  const int rg   = lane >> 4;      // MFMA frag k-group within frag
  const int rb   = lane & 15;      // MFMA frag non-K index
  const int b0   = blockIdx.x * 16;

  // zero h state (bf16 zero == 0 bits)
  for (int i = tid; i < 8 * AHK; i += 256) { aH0[i] = 0; aH1[i] = 0; }
  if (tid < 16) prevs[tid] = 0.f;
  float h0own[4] = {0.f, 0.f, 0.f, 0.f}, h1own[4] = {0.f, 0.f, 0.f, 0.f};

  bf16x8 wB[3][3][2][2];   // [matrix][nt_local][kf][split] - persistent VGPRs

  for (int ph = 0; ph < 2; ++ph) {
    // ---- load this phase's weight fragments (enc: mtx 0..2, dec: 3..5) ----
#pragma unroll
    for (int m = 0; m < 3; ++m)
#pragma unroll
      for (int ntl = 0; ntl < 3; ++ntl)
#pragma unroll
        for (int kf = 0; kf < 2; ++kf)
#pragma unroll
          for (int sp = 0; sp < 2; ++sp) {
            int mtx = ph * 3 + m;
            int nt = w * 3 + ntl;
            wB[m][ntl][kf][sp] = *(const bf16x8*)(p.wt +
                ((((mtx * 12 + nt) * 2 + kf) * 2 + sp) << 9) + lane * 8);
          }
    // ---- per-gate-thread constants ----
    float bi0[3], bh0[3], bi1[3], bh1[3], wxa[3], wxb[3];
#pragma unroll
    for (int g = 0; g < 3; ++g) {
      int r = g * 64 + j;
      if (ph == 0) {
        bi0[g] = p.bih0e[r]; bh0[g] = p.bhh0e[r];
        bi1[g] = p.bih1e[r]; bh1[g] = p.bhh1e[r];
        wxa[g] = p.wih0e[2 * r]; wxb[g] = p.wih0e[2 * r + 1];
      } else {
        bi0[g] = p.bih0d[r]; bh0[g] = p.bhh0d[r];
        bi1[g] = p.bih1d[r]; bh1[g] = p.bhh1d[r];
        wxa[g] = p.wih0d[r]; wxb[g] = 0.f;
      }
    }
    const float oW = p.outW[j], ob = p.outb[0];
    const int T = ph ? 180 : 512;
    __syncthreads();

    for (int t = 0; t < T; ++t) {
      // ========== P1: cell0 GEMM (Whh0 . h0) ==========
      float2 xx[4];
      if (ph == 0) {
#pragma unroll
        for (int i = 0; i < 4; ++i)
          xx[i] = *(const float2*)(p.x + ((size_t)(b0 + w * 4 + i) * 512 + t) * 2);
      }
      {
        bf16x8 a[2][2];
#pragma unroll
        for (int kf = 0; kf < 2; ++kf)
#pragma unroll
          for (int sp = 0; sp < 2; ++sp)
            a[kf][sp] = *(const bf16x8*)&aH0[(kf * 4 + rg) * AHK + rb * AHS + sp * 8];
#pragma unroll
        for (int ntl = 0; ntl < 3; ++ntl) {
          f32x4 acc = {0.f, 0.f, 0.f, 0.f};
#pragma unroll
          for (int kf = 0; kf < 2; ++kf) {
            acc = mfma16(a[kf][0], wB[0][ntl][kf][0], acc);
            acc = mfma16(a[kf][0], wB[0][ntl][kf][1], acc);
            acc = mfma16(a[kf][1], wB[0][ntl][kf][0], acc);
            acc = mfma16(a[kf][1], wB[0][ntl][kf][1], acc);
          }
          int row = (w * 3 + ntl) * 16 + rb;
#pragma unroll
          for (int r = 0; r < 4; ++r)
            exI[row * EXS + rg * 4 + r] = acc[r];
        }
      }
      __syncthreads();  // 1: exI(cell0) ready
      // ========== P2: gate0 (4 batches per thread-row) ==========
#pragma unroll
      for (int i = 0; i < 4; ++i) {
        int b = w * 4 + i;
        float sr = exI[j * EXS + b];
        float sz = exI[(64 + j) * EXS + b];
        float sn = exI[(128 + j) * EXS + b];
        float ir, iz, inn;
        if (ph == 0) {
          ir  = bi0[0] + wxa[0] * xx[i].x + wxb[0] * xx[i].y;
          iz  = bi0[1] + wxa[1] * xx[i].x + wxb[1] * xx[i].y;
          inn = bi0[2] + wxa[2] * xx[i].x + wxb[2] * xx[i].y;
        } else {
          float pv = prevs[b];
          ir  = bi0[0] + wxa[0] * pv;
          iz  = bi0[1] + wxa[1] * pv;
          inn = bi0[2] + wxa[2] * pv;
        }
        float r = sgm(ir + bh0[0] + sr);
        float z = sgm(iz + bh0[1] + sz);
        float n = th(inn + r * (bh0[2] + sn));
        h0own[i] = (1.f - z) * n + z * h0own[i];
        unsigned short hi = rbf(h0own[i]);
        unsigned short lo = rbf(h0own[i] - ubf(hi));
        int base = (j >> 3) * AHK + b * AHS + (j & 7);
        aH0[base]     = hi;
        aH0[base + 8] = lo;
      }
      __syncthreads();  // 2: aH0(new) ready
      // ========== P3: cell1 dual GEMM (Wih1 . h0new ; Whh1 . h1) ==========
      {
        bf16x8 a[2][2];
#pragma unroll
        for (int kf = 0; kf < 2; ++kf)
#pragma unroll
          for (int sp = 0; sp < 2; ++sp)
            a[kf][sp] = *(const bf16x8*)&aH0[(kf * 4 + rg) * AHK + rb * AHS + sp * 8];
#pragma unroll
        for (int ntl = 0; ntl < 3; ++ntl) {
          f32x4 acc = {0.f, 0.f, 0.f, 0.f};
#pragma unroll
          for (int kf = 0; kf < 2; ++kf) {
            acc = mfma16(a[kf][0], wB[1][ntl][kf][0], acc);
            acc = mfma16(a[kf][0], wB[1][ntl][kf][1], acc);
            acc = mfma16(a[kf][1], wB[1][ntl][kf][0], acc);
            acc = mfma16(a[kf][1], wB[1][ntl][kf][1], acc);
          }
          int row = (w * 3 + ntl) * 16 + rb;
#pragma unroll
          for (int r = 0; r < 4; ++r)
            exI[row * EXS + rg * 4 + r] = acc[r];
        }
#pragma unroll
        for (int kf = 0; kf < 2; ++kf)
#pragma unroll
          for (int sp = 0; sp < 2; ++sp)
            a[kf][sp] = *(const bf16x8*)&aH1[(kf * 4 + rg) * AHK + rb * AHS + sp * 8];
#pragma unroll
        for (int ntl = 0; ntl < 3; ++ntl) {
          f32x4 acc = {0.f, 0.f, 0.f, 0.f};
#pragma unroll
          for (int kf = 0; kf < 2; ++kf) {
            acc = mfma16(a[kf][0], wB[2][ntl][kf][0], acc);
            acc = mfma16(a[kf][0], wB[2][ntl][kf][1], acc);
            acc = mfma16(a[kf][1], wB[2][ntl][kf][0], acc);
            acc = mfma16(a[kf][1], wB[2][ntl][kf][1], acc);
          }
          int row = (w * 3 + ntl) * 16 + rb;
#pragma unroll
          for (int r = 0; r < 4; ++r)
            exH[row * EXS + rg * 4 + r] = acc[r];
        }
      }
      __syncthreads();  // 3: exI/exH(cell1) ready
      // ========== P4: gate1 (+ decoder output) ==========
      float v[4];
#pragma unroll
      for (int i = 0; i < 4; ++i) {
        int b = w * 4 + i;
        float air = exI[j * EXS + b],        ahr = exH[j * EXS + b];
        float aiz = exI[(64 + j) * EXS + b], ahz = exH[(64 + j) * EXS + b];
        float ain = exI[(128 + j) * EXS + b], ahn = exH[(128 + j) * EXS + b];
        float r = sgm(air + ahr + bi1[0] + bh1[0]);
        float z = sgm(aiz + ahz + bi1[1] + bh1[1]);
        float n = th(ain + bi1[2] + r * (bh1[2] + ahn));
        h1own[i] = (1.f - z) * n + z * h1own[i];
        unsigned short hi = rbf(h1own[i]);
        unsigned short lo = rbf(h1own[i] - ubf(hi));
        int base = (j >> 3) * AHK + b * AHS + (j & 7);
        aH1[base]     = hi;
        aH1[base + 8] = lo;
        v[i] = oW * h1own[i];
      }
      if (ph == 1) {
#pragma unroll
        for (int off = 32; off >= 1; off >>= 1)
#pragma unroll
          for (int i = 0; i < 4; ++i) v[i] += __shfl_xor(v[i], off, 64);
        if (j == 0) {
#pragma unroll
          for (int i = 0; i < 4; ++i) {
            float o = v[i] + ob;
            p.out[(size_t)(b0 + w * 4 + i) * 180 + t] = o;
            prevs[w * 4 + i] = o;             // autoregressive feedback
          }
        }
      }
      __syncthreads();  // 4: ex/aH1/prevs stable for next step
    }
  }
}

extern "C" void kernel_launch(void* const* d_in, const int* in_sizes, int n_in,
                              void* d_out, int out_size, void* d_ws, size_t ws_size,
                              hipStream_t stream) {
  // input order: 0 x, 1 enc_Wih0, 2 enc_Whh0, 3 enc_bih0, 4 enc_bhh0,
  // 5 enc_Wih1, 6 enc_Whh1, 7 enc_bih1, 8 enc_bhh1, 9 dec_Wih0, 10 dec_Whh0,
  // 11 dec_bih0, 12 dec_bhh0, 13 dec_Wih1, 14 dec_Whh1, 15 dec_bih1,
  // 16 dec_bhh1, 17 out_W, 18 out_b
  unsigned short* wt = (unsigned short*)d_ws;  // 6*24576*2 = 294912 B

  prep_w<<<dim3(6), dim3(256), 0, stream>>>(
      (const float*)d_in[2], (const float*)d_in[5], (const float*)d_in[6],
      (const float*)d_in[10], (const float*)d_in[13], (const float*)d_in[14], wt);

  Params p;
  p.x = (const float*)d_in[0];
  p.wih0e = (const float*)d_in[1];
  p.bih0e = (const float*)d_in[3];
  p.bhh0e = (const float*)d_in[4];
  p.bih1e = (const float*)d_in[7];
  p.bhh1e = (const float*)d_in[8];
  p.wih0d = (const float*)d_in[9];
  p.bih0d = (const float*)d_in[11];
  p.bhh0d = (const float*)d_in[12];
  p.bih1d = (const float*)d_in[15];
  p.bhh1d = (const float*)d_in[16];
  p.outW = (const float*)d_in[17];
  p.outb = (const float*)d_in[18];
  p.wt = wt;
  p.out = (float*)d_out;

  gru_main<<<dim3(512), dim3(256), 0, stream>>>(p);
}

// Round 4
// 2153.659 us; speedup vs baseline: 5.3952x; 1.1444x over previous
//
#include <hip/hip_runtime.h>

// GRU encoder-decoder, MFMA split-precision, ownership-aligned design (r4).
// B=8192, H=64, 512 enc + 180 dec steps. 512 blocks x 256 threads (4 waves),
// 16 batches/block. Wave w computes N-tiles {w, 4+w, 8+w} of each GEMM, so
// lane (rg,jc) holds r/z/n pre-activations for (batch=4*rg+reg, j=16*w+jc)
// in its three accumulators -> gate math is lane-local, no score exchange,
// 2 barriers/step (was 4), LDS down to 2x2x4KB A-frag buffers + 64B.
// h0/h1 fp32 state lives in the same lanes as the gate outputs; only the
// bf16 hi/lo A-fragments round-trip LDS (XOR-swizzled b^rg: frag reads are
// quarter-wave-linear, writes <=2-way). lo*lo MFMA product dropped (2^-18).
// amdgpu_waves_per_eu(2,2) pins 2 waves/SIMD so the 36 weight fragments
// (144 VGPR) stay register-resident (r3's VGPR=128 proved the compiler was
// re-fetching weights from L2 every step).

typedef __attribute__((ext_vector_type(8))) short bf16x8;
typedef __attribute__((ext_vector_type(4))) float f32x4;

struct Params {
  const float *x;
  const float *wih0e, *bih0e, *bhh0e, *bih1e, *bhh1e;
  const float *wih0d, *bih0d, *bhh0d, *bih1d, *bhh1d;
  const float *outW, *outb;
  const unsigned short *wt;   // [6][12 nt][2 kf][2 sp][64 lane][8 e] bf16 frags
  float *out;
};

__device__ __forceinline__ float sgm(float v) { return 1.f / (1.f + __expf(-v)); }
__device__ __forceinline__ float th(float v)  { float e = __expf(2.f * v); return 1.f - 2.f / (e + 1.f); }

// fp32 -> bf16 round-to-nearest-even (bit trick)
__device__ __forceinline__ unsigned short rbf(float v) {
  unsigned int u = __float_as_uint(v);
  return (unsigned short)((u + 0x7fffu + ((u >> 16) & 1u)) >> 16);
}
__device__ __forceinline__ float ubf(unsigned short h) {
  return __uint_as_float((unsigned int)h << 16);
}

__device__ __forceinline__ f32x4 mfma16(bf16x8 a, bf16x8 b, f32x4 c) {
  return __builtin_amdgcn_mfma_f32_16x16x32_bf16(a, b, c, 0, 0, 0);
}

// Preprocess the six 192x64 fp32 matrices into B-fragment bf16 hi/lo planes.
// B[k][n] = W[n][k]; frag (nt,kf,sp): lane l elem e holds
// B[k = kf*32 + (l>>4)*8 + e][n = nt*16 + (l&15)].
// Flat: dst[m][ ((nt*2+kf)*2+sp)*512 + l*8 + e ]   (validated in r3)
__global__ void prep_w(const float* s0, const float* s1, const float* s2,
                       const float* s3, const float* s4, const float* s5,
                       unsigned short* dst) {
  const float* srcs[6] = {s0, s1, s2, s3, s4, s5};
  const float* s = srcs[blockIdx.x];
  unsigned short* o = dst + blockIdx.x * 24576;
  for (int i = threadIdx.x; i < 24576; i += blockDim.x) {
    int e  = i & 7;
    int l  = (i >> 3) & 63;
    int sp = (i >> 9) & 1;
    int kf = (i >> 10) & 1;
    int nt = i >> 11;
    int n = nt * 16 + (l & 15);
    int k = kf * 32 + (l >> 4) * 8 + e;
    float v = s[n * 64 + k];
    unsigned short hi = rbf(v);
    unsigned short val = hi;
    if (sp) val = rbf(v - ubf(hi));
    o[i] = val;
  }
}

// A-frag LDS layout (per h matrix, per parity buffer), 2048 ushorts = 4KB:
//   idx(kf,sp,rg,bslot,e) = (kf*2+sp)*512 + rg*128 + bslot*8 + e
//   stored value = h_split[sp][b = bslot ^ rg][k = kf*32 + rg*8 + e]
// Read (lane l): rg=l>>4, bslot=(l&15)^rg  -> b128, quarter-wave linear.
// Write (lane j-owner): kf=j>>5, rg=(j>>3)&3, e=j&7, bslot=b^rg -> <=2-way.

__global__ __launch_bounds__(256) __attribute__((amdgpu_waves_per_eu(2, 2)))
void gru_main(Params p) {
  __shared__ unsigned short aH0[2][2048];
  __shared__ unsigned short aH1[2][2048];
  __shared__ float pw[4][16];

  const int tid = threadIdx.x;
  const int l   = tid & 63;
  const int w   = tid >> 6;        // wave 0..3
  const int jc  = l & 15;
  const int rg  = l >> 4;
  const int j   = w * 16 + jc;     // this lane's hidden/gate index
  const int b0  = blockIdx.x * 16;

  // write-side frag coords (k = j)
  const int kfj = j >> 5, rgj = (j >> 3) & 3, ej = j & 7;
  const int wbase = kfj * 1024 + rgj * 128 + ej;     // +bslot*8; +512 for lo
  // read-side base: + (kf*2+sp)*512
  const int rdb = rg * 128 + ((jc ^ rg) << 3);

  for (int i = tid; i < 2048; i += 256) {
    aH0[0][i] = 0; aH0[1][i] = 0; aH1[0][i] = 0; aH1[1][i] = 0;
  }
  float h0own[4] = {0.f, 0.f, 0.f, 0.f}, h1own[4] = {0.f, 0.f, 0.f, 0.f};

  bf16x8 wB[3][3][2][2];   // [matrix][gate-tile g][kf][split] persistent VGPRs

  for (int ph = 0; ph < 2; ++ph) {
    // ---- load this phase's weight fragments; tile for gate g is g*4+w ----
#pragma unroll
    for (int m = 0; m < 3; ++m)
#pragma unroll
      for (int g = 0; g < 3; ++g)
#pragma unroll
        for (int kf = 0; kf < 2; ++kf)
#pragma unroll
          for (int sp = 0; sp < 2; ++sp) {
            int nt = g * 4 + w;
            wB[m][g][kf][sp] = *(const bf16x8*)(p.wt +
                (((((ph * 3 + m) * 12 + nt) * 2 + kf) * 2 + sp) << 9) + l * 8);
          }
    // ---- per-lane constants for row j ----
    float bi0[3], bh0[3], bi1[3], bh1[3], wxa[3], wxb[3];
#pragma unroll
    for (int g = 0; g < 3; ++g) {
      int r = g * 64 + j;
      if (ph == 0) {
        bi0[g] = p.bih0e[r]; bh0[g] = p.bhh0e[r];
        bi1[g] = p.bih1e[r]; bh1[g] = p.bhh1e[r];
        wxa[g] = p.wih0e[2 * r]; wxb[g] = p.wih0e[2 * r + 1];
      } else {
        bi0[g] = p.bih0d[r]; bh0[g] = p.bhh0d[r];
        bi1[g] = p.bih1d[r]; bh1[g] = p.bhh1d[r];
        wxa[g] = p.wih0d[r]; wxb[g] = 0.f;
      }
    }
    const float oW = p.outW[j], ob = p.outb[0];
    const int T = ph ? 180 : 512;
    __syncthreads();

    for (int t = 0; t < T; ++t) {
      const int cur = t & 1;
      // ---- inputs: x (enc) / prev from pw partials (dec) ----
      float2 xx[4]; float prevv[4];
      if (ph == 0) {
#pragma unroll
        for (int i = 0; i < 4; ++i)
          xx[i] = *(const float2*)(p.x + ((size_t)(b0 + rg * 4 + i) * 512 + t) * 2);
      } else {
        if (t > 0) {
#pragma unroll
          for (int i = 0; i < 4; ++i)
            prevv[i] = ob + pw[0][rg * 4 + i] + pw[1][rg * 4 + i]
                          + pw[2][rg * 4 + i] + pw[3][rg * 4 + i];
          if (w == 0 && jc == 0) {
#pragma unroll
            for (int i = 0; i < 4; ++i)
              p.out[(size_t)(b0 + rg * 4 + i) * 180 + (t - 1)] = prevv[i];
          }
        } else {
#pragma unroll
          for (int i = 0; i < 4; ++i) prevv[i] = 0.f;
        }
      }
      // ---- cell0 GEMM: Whh0 . h0(old); 3 lane-local gate accumulators ----
      const unsigned short* h0o = aH0[cur ^ 1];
      f32x4 aR = {0,0,0,0}, aZ = {0,0,0,0}, aN = {0,0,0,0};
#pragma unroll
      for (int kf = 0; kf < 2; ++kf) {
        bf16x8 ah = *(const bf16x8*)&h0o[kf * 1024 + rdb];
        bf16x8 al = *(const bf16x8*)&h0o[kf * 1024 + 512 + rdb];
        aR = mfma16(ah, wB[0][0][kf][0], aR);
        aZ = mfma16(ah, wB[0][1][kf][0], aZ);
        aN = mfma16(ah, wB[0][2][kf][0], aN);
        aR = mfma16(al, wB[0][0][kf][0], aR);
        aZ = mfma16(al, wB[0][1][kf][0], aZ);
        aN = mfma16(al, wB[0][2][kf][0], aN);
        aR = mfma16(ah, wB[0][0][kf][1], aR);
        aZ = mfma16(ah, wB[0][1][kf][1], aZ);
        aN = mfma16(ah, wB[0][2][kf][1], aN);
      }
      // ---- gate0 (lane-local), publish h0(new) frags ----
      unsigned short* h0n = aH0[cur];
#pragma unroll
      for (int i = 0; i < 4; ++i) {
        float xr, xz, xn;
        if (ph == 0) {
          xr = bi0[0] + wxa[0] * xx[i].x + wxb[0] * xx[i].y;
          xz = bi0[1] + wxa[1] * xx[i].x + wxb[1] * xx[i].y;
          xn = bi0[2] + wxa[2] * xx[i].x + wxb[2] * xx[i].y;
        } else {
          xr = bi0[0] + wxa[0] * prevv[i];
          xz = bi0[1] + wxa[1] * prevv[i];
          xn = bi0[2] + wxa[2] * prevv[i];
        }
        float r = sgm(xr + bh0[0] + aR[i]);
        float z = sgm(xz + bh0[1] + aZ[i]);
        float n = th(xn + r * (bh0[2] + aN[i]));
        h0own[i] = (1.f - z) * n + z * h0own[i];
        unsigned short hi = rbf(h0own[i]);
        unsigned short lo = rbf(h0own[i] - ubf(hi));
        int idx = wbase + (((rg * 4 + i) ^ rgj) << 3);
        h0n[idx] = hi; h0n[idx + 512] = lo;
      }
      __syncthreads();   // mid: h0(new) frags complete
      // ---- cell1 dual GEMM: Wih1 . h0(new) ; Whh1 . h1(old) ----
      const unsigned short* h1o = aH1[cur ^ 1];
      f32x4 iR = {0,0,0,0}, iZ = {0,0,0,0}, iN = {0,0,0,0};
      f32x4 hR = {0,0,0,0}, hZ = {0,0,0,0}, hN = {0,0,0,0};
#pragma unroll
      for (int kf = 0; kf < 2; ++kf) {
        bf16x8 gh = *(const bf16x8*)&h0n[kf * 1024 + rdb];
        bf16x8 gl = *(const bf16x8*)&h0n[kf * 1024 + 512 + rdb];
        bf16x8 qh = *(const bf16x8*)&h1o[kf * 1024 + rdb];
        bf16x8 ql = *(const bf16x8*)&h1o[kf * 1024 + 512 + rdb];
        iR = mfma16(gh, wB[1][0][kf][0], iR);
        hR = mfma16(qh, wB[2][0][kf][0], hR);
        iZ = mfma16(gh, wB[1][1][kf][0], iZ);
        hZ = mfma16(qh, wB[2][1][kf][0], hZ);
        iN = mfma16(gh, wB[1][2][kf][0], iN);
        hN = mfma16(qh, wB[2][2][kf][0], hN);
        iR = mfma16(gl, wB[1][0][kf][0], iR);
        hR = mfma16(ql, wB[2][0][kf][0], hR);
        iZ = mfma16(gl, wB[1][1][kf][0], iZ);
        hZ = mfma16(ql, wB[2][1][kf][0], hZ);
        iN = mfma16(gl, wB[1][2][kf][0], iN);
        hN = mfma16(ql, wB[2][2][kf][0], hN);
        iR = mfma16(gh, wB[1][0][kf][1], iR);
        hR = mfma16(qh, wB[2][0][kf][1], hR);
        iZ = mfma16(gh, wB[1][1][kf][1], iZ);
        hZ = mfma16(qh, wB[2][1][kf][1], hZ);
        iN = mfma16(gh, wB[1][2][kf][1], iN);
        hN = mfma16(qh, wB[2][2][kf][1], hN);
      }
      // ---- gate1 (lane-local), publish h1(new) frags, decoder partials ----
      unsigned short* h1n = aH1[cur];
      float v[4];
#pragma unroll
      for (int i = 0; i < 4; ++i) {
        float r = sgm(iR[i] + hR[i] + bi1[0] + bh1[0]);
        float z = sgm(iZ[i] + hZ[i] + bi1[1] + bh1[1]);
        float n = th(iN[i] + bi1[2] + r * (bh1[2] + hN[i]));
        h1own[i] = (1.f - z) * n + z * h1own[i];
        unsigned short hi = rbf(h1own[i]);
        unsigned short lo = rbf(h1own[i] - ubf(hi));
        int idx = wbase + (((rg * 4 + i) ^ rgj) << 3);
        h1n[idx] = hi; h1n[idx + 512] = lo;
        v[i] = oW * h1own[i];
      }
      if (ph == 1) {
        // out partial: sum over this wave's 16 j's (lanes share rg group)
#pragma unroll
        for (int off = 1; off < 16; off <<= 1)
#pragma unroll
          for (int i = 0; i < 4; ++i) v[i] += __shfl_xor(v[i], off, 64);
        if (jc == 0) {
#pragma unroll
          for (int i = 0; i < 4; ++i) pw[w][rg * 4 + i] = v[i];
        }
      }
      __syncthreads();   // end: h1(new) frags + pw complete
    }
    // ---- decoder tail: emit out[179] from last partials ----
    if (ph == 1) {
      if (w == 0 && jc == 0) {
#pragma unroll
        for (int i = 0; i < 4; ++i) {
          float fv = ob + pw[0][rg * 4 + i] + pw[1][rg * 4 + i]
                        + pw[2][rg * 4 + i] + pw[3][rg * 4 + i];
          p.out[(size_t)(b0 + rg * 4 + i) * 180 + 179] = fv;
        }
      }
    }
  }
}

extern "C" void kernel_launch(void* const* d_in, const int* in_sizes, int n_in,
                              void* d_out, int out_size, void* d_ws, size_t ws_size,
                              hipStream_t stream) {
  // input order: 0 x, 1 enc_Wih0, 2 enc_Whh0, 3 enc_bih0, 4 enc_bhh0,
  // 5 enc_Wih1, 6 enc_Whh1, 7 enc_bih1, 8 enc_bhh1, 9 dec_Wih0, 10 dec_Whh0,
  // 11 dec_bih0, 12 dec_bhh0, 13 dec_Wih1, 14 dec_Whh1, 15 dec_bih1,
  // 16 dec_bhh1, 17 out_W, 18 out_b
  unsigned short* wt = (unsigned short*)d_ws;  // 6*24576*2 = 294912 B

  prep_w<<<dim3(6), dim3(256), 0, stream>>>(
      (const float*)d_in[2], (const float*)d_in[5], (const float*)d_in[6],
      (const float*)d_in[10], (const float*)d_in[13], (const float*)d_in[14], wt);

  Params p;
  p.x = (const float*)d_in[0];
  p.wih0e = (const float*)d_in[1];
  p.bih0e = (const float*)d_in[3];
  p.bhh0e = (const float*)d_in[4];
  p.bih1e = (const float*)d_in[7];
  p.bhh1e = (const float*)d_in[8];
  p.wih0d = (const float*)d_in[9];
  p.bih0d = (const float*)d_in[11];
  p.bhh0d = (const float*)d_in[12];
  p.bih1d = (const float*)d_in[15];
  p.bhh1d = (const float*)d_in[16];
  p.outW = (const float*)d_in[17];
  p.outb = (const float*)d_in[18];
  p.wt = wt;
  p.out = (float*)d_out;

  gru_main<<<dim3(512), dim3(256), 0, stream>>>(p);
}